// Round 17
// baseline (269.353 us; speedup 1.0000x reference)
//
#include <hip/hip_runtime.h>

constexpr int NN = 50000;
constexpr int NE = 800000;
constexpr int C = 64;        // EIN == HID == OUT == 64
constexpr int IN_DIM = 128;
constexpr float NEG = 0.2f;
constexpr int NB = (NN + 255) / 256;     // 196 blocks
constexpr int FEATB = (NN + 127) / 128;  // 391 feat blocks

typedef __attribute__((ext_vector_type(8))) short short8;
typedef __attribute__((ext_vector_type(4))) float f32x4;

// ---- pure-integer bf16 conversions (no HIP bf16 structs) ----
__device__ __forceinline__ unsigned short f2bf(float f) {
    unsigned u = __float_as_uint(f);
    unsigned r = 0x7FFFu + ((u >> 16) & 1u);
    return (unsigned short)((u + r) >> 16);
}
__device__ __forceinline__ unsigned pack_bf2(float a, float b) {
    return (unsigned)f2bf(a) | ((unsigned)f2bf(b) << 16);
}
__device__ __forceinline__ float bf2f(unsigned u) {
    return __uint_as_float(u << 16);
}

// ============================================================
// Fused setup: zero hist/bagg, batch passthrough, small vecs.
// ============================================================
__global__ __launch_bounds__(256) void k_setup(
        const float* __restrict__ We1, const float* __restrict__ ae1v,
        const float* __restrict__ We2, const float* __restrict__ ae2v,
        const float* __restrict__ W1, const float* __restrict__ as1,
        const float* __restrict__ ad1,
        const float* __restrict__ W2, const float* __restrict__ as2,
        const float* __restrict__ ad2,
        const int* __restrict__ batch,
        float* __restrict__ vecs, int* __restrict__ hist, int* __restrict__ bagg,
        float* __restrict__ out_b) {
    int t = blockIdx.x * 256 + threadIdx.x;
    if (t < 512) {
        const float* M; const float* v; int row;
        if      (t < 64)  { M = We1; v = ae1v; row = t; }
        else if (t < 128) { M = We2; v = ae2v; row = t - 64; }
        else if (t < 256) { M = W1;  v = as1;  row = t - 128; }
        else if (t < 384) { M = W1;  v = ad1;  row = t - 256; }
        else if (t < 448) { M = W2;  v = as2;  row = t - 384; }
        else              { M = W2;  v = ad2;  row = t - 448; }
        float s = 0.f;
        #pragma unroll
        for (int c = 0; c < 64; ++c) s += M[row * 64 + c] * v[c];
        vecs[t] = s;
    }
    if (t < NN) { hist[t] = 0; out_b[t] = (float)batch[t]; }
    if (t < NB) bagg[t] = 0;
}

// ============================================================
// MLP body: fused 2-layer edge MLP via MFMA bf16 (swapped
// operands) + fp32 ae dots + dst hist. 128 edges, 256 threads.
// ============================================================
__device__ __forceinline__ void mlp_body(char* __restrict__ LDSB, int bid,
        const float* __restrict__ ea, const int* __restrict__ dst,
        const float* __restrict__ Wm1, const float* __restrict__ bm1,
        const float* __restrict__ Wm2, const float* __restrict__ bm2,
        const float* __restrict__ wv,
        float* __restrict__ eout, float* __restrict__ ae1, float* __restrict__ ae2,
        int* __restrict__ hist) {
    constexpr int AP = 144;              // bytes per LDS row: (64+8) bf16
    char* Atile = LDSB;                  // 18 KB
    char* Bt1 = LDSB + 128 * AP;         // 9 KB
    char* Bt2 = Bt1 + 64 * AP;           // 9 KB
    const int t = threadIdx.x;
    const long long E0 = (long long)bid * 128;
    const int l = t & 63;

    if (t < 128) atomicAdd(&hist[dst[E0 + t]], 1);

    // stage A tile (coalesced nt float4) + fp32 ae dots
    {
        const int j = t & 15;
        const int eb = t >> 4;
        float4 wk1 = *(const float4*)&wv[j * 4];
        float4 wk2 = *(const float4*)&wv[64 + j * 4];
        const f32x4* g = (const f32x4*)(ea + E0 * 64);
        float s1[8], s2[8];
        #pragma unroll
        for (int q = 0; q < 8; ++q) {
            f32x4 v = __builtin_nontemporal_load(&g[t + 256 * q]);
            int e = eb + 16 * q;
            s1[q] = v[0] * wk1.x + v[1] * wk1.y + v[2] * wk1.z + v[3] * wk1.w;
            s2[q] = v[0] * wk2.x + v[1] * wk2.y + v[2] * wk2.z + v[3] * wk2.w;
            uint2 wr;
            wr.x = pack_bf2(v[0], v[1]);
            wr.y = pack_bf2(v[2], v[3]);
            *(uint2*)(Atile + e * AP + j * 8) = wr;
        }
        #pragma unroll
        for (int off = 1; off < 16; off <<= 1) {
            #pragma unroll
            for (int q = 0; q < 8; ++q) {
                s1[q] += __shfl_xor(s1[q], off);
                s2[q] += __shfl_xor(s2[q], off);
            }
        }
        float o1 = 0.f, o2 = 0.f;
        #pragma unroll
        for (int q = 0; q < 8; ++q) {
            if (j == q)     o1 = s1[q];
            if (j == q + 8) o2 = s2[q];
        }
        if (j < 8) ae1[E0 + eb + 16 * j] = o1;
        else       ae2[E0 + eb + 16 * (j - 8)] = o2;
    }
    // stage Bt1/Bt2 = W^T bf16
    {
        const int c = t & 63, kq = t >> 6;
        #pragma unroll
        for (int i = 0; i < 16; i += 2) {
            int k = kq * 16 + i;
            *(unsigned*)(Bt1 + c * AP + k * 2) = pack_bf2(Wm1[k * 64 + c], Wm1[(k + 1) * 64 + c]);
            *(unsigned*)(Bt2 + c * AP + k * 2) = pack_bf2(Wm2[k * 64 + c], Wm2[(k + 1) * 64 + c]);
        }
    }
    __syncthreads();

    const int m0 = (t >> 6) * 32;
    const int lr = l & 15;
    const int lq = l >> 4;
    const int lk = lq * 8;

    f32x4 acc[4][2] = {};
    #pragma unroll
    for (int ks = 0; ks < 2; ++ks) {
        int ko = ks * 32 + lk;
        short8 a0 = *(const short8*)(Atile + (m0 + lr) * AP + ko * 2);
        short8 a1 = *(const short8*)(Atile + (m0 + 16 + lr) * AP + ko * 2);
        #pragma unroll
        for (int ct = 0; ct < 4; ++ct) {
            short8 b = *(const short8*)(Bt1 + (ct * 16 + lr) * AP + ko * 2);
            acc[ct][0] = __builtin_amdgcn_mfma_f32_16x16x32_bf16(b, a0, acc[ct][0], 0, 0, 0);
            acc[ct][1] = __builtin_amdgcn_mfma_f32_16x16x32_bf16(b, a1, acc[ct][1], 0, 0, 0);
        }
    }
    #pragma unroll
    for (int ct = 0; ct < 4; ++ct) {
        float4 bv = *(const float4*)&bm1[ct * 16 + lq * 4];
        #pragma unroll
        for (int et = 0; et < 2; ++et) {
            float v0 = fmaxf(acc[ct][et][0] + bv.x, 0.f);
            float v1 = fmaxf(acc[ct][et][1] + bv.y, 0.f);
            float v2 = fmaxf(acc[ct][et][2] + bv.z, 0.f);
            float v3 = fmaxf(acc[ct][et][3] + bv.w, 0.f);
            uint2 w;
            w.x = pack_bf2(v0, v1);
            w.y = pack_bf2(v2, v3);
            int e = m0 + et * 16 + lr;
            *(uint2*)(Atile + e * AP + (ct * 16 + lq * 4) * 2) = w;
        }
    }
    f32x4 acc2[4][2] = {};
    #pragma unroll
    for (int ks = 0; ks < 2; ++ks) {
        int ko = ks * 32 + lk;
        short8 a0 = *(const short8*)(Atile + (m0 + lr) * AP + ko * 2);
        short8 a1 = *(const short8*)(Atile + (m0 + 16 + lr) * AP + ko * 2);
        #pragma unroll
        for (int ct = 0; ct < 4; ++ct) {
            short8 b = *(const short8*)(Bt2 + (ct * 16 + lr) * AP + ko * 2);
            acc2[ct][0] = __builtin_amdgcn_mfma_f32_16x16x32_bf16(b, a0, acc2[ct][0], 0, 0, 0);
            acc2[ct][1] = __builtin_amdgcn_mfma_f32_16x16x32_bf16(b, a1, acc2[ct][1], 0, 0, 0);
        }
    }
    #pragma unroll
    for (int ct = 0; ct < 4; ++ct) {
        float4 bv = *(const float4*)&bm2[ct * 16 + lq * 4];
        #pragma unroll
        for (int et = 0; et < 2; ++et) {
            int e = m0 + et * 16 + lr;
            float4 o;
            o.x = acc2[ct][et][0] + bv.x;
            o.y = acc2[ct][et][1] + bv.y;
            o.z = acc2[ct][et][2] + bv.z;
            o.w = acc2[ct][et][3] + bv.w;
            *(float4*)&eout[(E0 + e) * 64 + ct * 16 + lq * 4] = o;
        }
    }
}

// ============================================================
// feat body (layer 1 only now): h = X @ W1 + fp32 dots.
// ============================================================
template <int K>
__device__ __forceinline__ void feat_body(char* __restrict__ LDSB, int bid,
        const float* __restrict__ xv, const float* __restrict__ W,
        const float* __restrict__ uv,
        unsigned short* __restrict__ h, float* __restrict__ asrc,
        float* __restrict__ adst, int M) {
    constexpr int AP = K * 2 + 16;
    constexpr int QW = K / 4;
    constexpr int NQ = K / 8;
    constexpr int EPQ = 256 / QW;
    char* Atile = LDSB;
    char* Bt = LDSB + 128 * AP;
    const int t = threadIdx.x;
    const int M0 = bid * 128;
    const int l = t & 63;

    {
        const int j = t % QW;
        const int eb = t / QW;
        float4 wk1 = *(const float4*)&uv[j * 4];
        float4 wk2 = *(const float4*)&uv[K + j * 4];
        float s1[NQ], s2[NQ];
        #pragma unroll
        for (int q = 0; q < NQ; ++q) {
            int e = eb + EPQ * q;
            const float4* g = (const float4*)xv + (long long)M0 * (K / 4);
            float4 v = make_float4(0.f, 0.f, 0.f, 0.f);
            if (M0 + e < M) v = g[t + 256 * q];
            uint2 wr;
            wr.x = pack_bf2(v.x, v.y);
            wr.y = pack_bf2(v.z, v.w);
            s1[q] = v.x * wk1.x + v.y * wk1.y + v.z * wk1.z + v.w * wk1.w;
            s2[q] = v.x * wk2.x + v.y * wk2.y + v.z * wk2.z + v.w * wk2.w;
            *(uint2*)(Atile + e * AP + j * 8) = wr;
        }
        #pragma unroll
        for (int off = 1; off < QW; off <<= 1) {
            #pragma unroll
            for (int q = 0; q < NQ; ++q) {
                s1[q] += __shfl_xor(s1[q], off);
                s2[q] += __shfl_xor(s2[q], off);
            }
        }
        float o1 = 0.f, o2 = 0.f;
        #pragma unroll
        for (int q = 0; q < NQ; ++q) {
            if (j == q)      o1 = s1[q];
            if (j == q + NQ) o2 = s2[q];
        }
        if (j < NQ) { int e = eb + EPQ * j;        if (M0 + e < M) asrc[M0 + e] = o1; }
        else        { int e = eb + EPQ * (j - NQ); if (M0 + e < M) adst[M0 + e] = o2; }
    }
    {
        const int c = t & 63, kq = t >> 6;
        #pragma unroll
        for (int i = 0; i < K / 4; i += 2) {
            int k = kq * (K / 4) + i;
            *(unsigned*)(Bt + c * AP + k * 2) = pack_bf2(W[k * 64 + c], W[(k + 1) * 64 + c]);
        }
    }
    __syncthreads();

    const int m0 = (t >> 6) * 32;
    const int lr = l & 15;
    const int lq = l >> 4;
    const int lk = lq * 8;

    f32x4 acc[4][2] = {};
    #pragma unroll
    for (int ks = 0; ks < K / 32; ++ks) {
        int ko = ks * 32 + lk;
        short8 a0 = *(const short8*)(Atile + (m0 + lr) * AP + ko * 2);
        short8 a1 = *(const short8*)(Atile + (m0 + 16 + lr) * AP + ko * 2);
        #pragma unroll
        for (int ct = 0; ct < 4; ++ct) {
            short8 b = *(const short8*)(Bt + (ct * 16 + lr) * AP + ko * 2);
            acc[ct][0] = __builtin_amdgcn_mfma_f32_16x16x32_bf16(b, a0, acc[ct][0], 0, 0, 0);
            acc[ct][1] = __builtin_amdgcn_mfma_f32_16x16x32_bf16(b, a1, acc[ct][1], 0, 0, 0);
        }
    }
    #pragma unroll
    for (int ct = 0; ct < 4; ++ct)
    #pragma unroll
    for (int et = 0; et < 2; ++et) {
        int row = m0 + et * 16 + lr;
        if (M0 + row < M) {
            uint2 w;
            w.x = pack_bf2(acc[ct][et][0], acc[ct][et][1]);
            w.y = pack_bf2(acc[ct][et][2], acc[ct][et][3]);
            *(uint2*)&h[(long long)(M0 + row) * 64 + ct * 16 + lq * 4] = w;
        }
    }
}

// ============================================================
// Fused launch: blocks [0,FEATB) run feat1, rest run MLP.
// ============================================================
__global__ __launch_bounds__(256) void k_mlp_feat(
        const float* __restrict__ ea, const int* __restrict__ dst,
        const float* __restrict__ Wm1, const float* __restrict__ bm1,
        const float* __restrict__ Wm2, const float* __restrict__ bm2,
        const float* __restrict__ wv,
        float* __restrict__ eout, float* __restrict__ ae1, float* __restrict__ ae2,
        int* __restrict__ hist,
        const float* __restrict__ x, const float* __restrict__ W1,
        const float* __restrict__ uv,
        unsigned short* __restrict__ h, float* __restrict__ asrc,
        float* __restrict__ adst) {
    __shared__ char LDSB[128 * (IN_DIM * 2 + 16) + 64 * (IN_DIM * 2 + 16)]; // 52224 B
    if (blockIdx.x < FEATB) {
        feat_body<IN_DIM>(LDSB, blockIdx.x, x, W1, uv, h, asrc, adst, NN);
    } else {
        mlp_body(LDSB, blockIdx.x - FEATB, ea, dst, Wm1, bm1, Wm2, bm2, wv,
                 eout, ae1, ae2, hist);
    }
}

// ============================================================
// Single-kernel decoupled-lookback exclusive scan (G16-safe).
// ============================================================
__global__ __launch_bounds__(256) void k_scan_f(const int* __restrict__ hist,
        int* __restrict__ row_ptr, int* __restrict__ cursor, int* __restrict__ bagg) {
    __shared__ int s[256];
    __shared__ int red[5];
    const int t = threadIdx.x, b = blockIdx.x;
    const int idx = b * 256 + t;
    int v = (idx < NN) ? hist[idx] : 0;
    s[t] = v;
    __syncthreads();
    #pragma unroll
    for (int off = 1; off < 256; off <<= 1) {
        int x = (t >= off) ? s[t - off] : 0;
        __syncthreads();
        s[t] += x;
        __syncthreads();
    }
    if (t == 255)
        __hip_atomic_store(&bagg[b], (s[255] << 1) | 1,
                           __ATOMIC_RELEASE, __HIP_MEMORY_SCOPE_AGENT);
    int contrib = 0;
    if (t < b) {
        int a;
        do {
            a = __hip_atomic_load(&bagg[t], __ATOMIC_ACQUIRE, __HIP_MEMORY_SCOPE_AGENT);
        } while (!(a & 1));
        contrib = a >> 1;
    }
    #pragma unroll
    for (int off = 32; off; off >>= 1) contrib += __shfl_down(contrib, off);
    if ((t & 63) == 0) red[t >> 6] = contrib;
    __syncthreads();
    if (t == 0) red[4] = red[0] + red[1] + red[2] + red[3];
    __syncthreads();
    int offset = red[4];
    if (idx < NN) {
        int rp = offset + s[t] - v;
        row_ptr[idx] = rp;
        cursor[idx] = rp;
    }
    if (idx == NN) row_ptr[NN] = NE;
}

// scatter 8-byte records: {src, ae1|ae2 packed bf16}
__global__ void k_scatter(const int* __restrict__ src, const int* __restrict__ dst,
                          const float* __restrict__ ae1, const float* __restrict__ ae2,
                          int* __restrict__ cursor, uint2* __restrict__ csr) {
    int t = blockIdx.x * blockDim.x + threadIdx.x;
    if (t >= NE) return;
    int d = dst[t];
    int pos = atomicAdd(&cursor[d], 1);
    csr[pos] = make_uint2((unsigned)src[t], pack_bf2(ae1[t], ae2[t]));
}

// ============================================================
// GAT aggregation: wave per node, 4 subgroups of 16 lanes each.
// IS_L1: fused layer-2 projection (h2 = elu(o) @ W2, dots) --
// writes h2 (bf16) + asrc2/adst2; no intermediate out1 buffer.
// ============================================================
template <bool IS_L1>
__global__ void k_gat(const int* __restrict__ row_ptr, const uint2* __restrict__ csr,
                      const float* __restrict__ asrc, const float* __restrict__ adst,
                      const unsigned short* __restrict__ h, const float* __restrict__ bias,
                      const float* __restrict__ W2, const float* __restrict__ uv2,
                      unsigned short* __restrict__ h2out, float* __restrict__ asrc2,
                      float* __restrict__ adst2, float* __restrict__ outf) {
    __shared__ float sh_o[4][64];
    int wv = threadIdx.x >> 6;
    int n = blockIdx.x * 4 + wv;
    if (n >= NN) return;
    int lane = threadIdx.x & 63;
    int g = lane >> 4, s = lane & 15;
    int beg = row_ptr[n], end = row_ptr[n + 1];
    float adn = adst[n];
    float m = -1e30f, l = 0.f, sum_ae = 0.f;
    float4 acc = make_float4(0.f, 0.f, 0.f, 0.f);

    int i = beg + g;
    uint2 rc = make_uint2(0u, 0u);
    ushort4 hu = make_ushort4(0, 0, 0, 0);
    float asv = 0.f;
    if (i < end) {
        rc = csr[i];
        hu = *(const ushort4*)&h[(long long)rc.x * 64 + s * 4];
        asv = asrc[rc.x];
    }
    for (; i < end; i += 4) {
        uint2 rn = rc; ushort4 hn = hu; float asn = asv;
        if (i + 4 < end) {
            rn = csr[i + 4];
            hn = *(const ushort4*)&h[(long long)rn.x * 64 + s * 4];
            asn = asrc[rn.x];
        }
        float ae = IS_L1 ? bf2f(rc.y & 0xFFFFu) : bf2f(rc.y >> 16);
        sum_ae += ae;
        float a = asv + adn + ae;
        a = a > 0.f ? a : NEG * a;
        float mn = fmaxf(m, a);
        float sc = __expf(m - mn), p = __expf(a - mn);
        l = l * sc + p;
        acc.x = acc.x * sc + p * bf2f(hu.x);
        acc.y = acc.y * sc + p * bf2f(hu.y);
        acc.z = acc.z * sc + p * bf2f(hu.z);
        acc.w = acc.w * sc + p * bf2f(hu.w);
        m = mn;
        rc = rn; hu = hn; asv = asn;
    }
    #pragma unroll
    for (int off = 16; off < 64; off <<= 1) {
        float mo = __shfl_xor(m, off);
        float lo = __shfl_xor(l, off);
        float ax = __shfl_xor(acc.x, off);
        float ay = __shfl_xor(acc.y, off);
        float az = __shfl_xor(acc.z, off);
        float aw = __shfl_xor(acc.w, off);
        float so = __shfl_xor(sum_ae, off);
        float mn = fmaxf(m, mo);
        float s1 = __expf(m - mn), s2 = __expf(mo - mn);
        l = l * s1 + lo * s2;
        acc.x = acc.x * s1 + ax * s2;
        acc.y = acc.y * s1 + ay * s2;
        acc.z = acc.z * s1 + az * s2;
        acc.w = acc.w * s1 + aw * s2;
        sum_ae += so;
        m = mn;
    }
    // self loop (ae_self = mean of incoming ae, by linearity)
    {
        float deg = (float)(end - beg);
        float ae = sum_ae / fmaxf(deg, 1.f);
        float a = asrc[n] + adn + ae;
        a = a > 0.f ? a : NEG * a;
        ushort4 hun = *(const ushort4*)&h[(long long)n * 64 + s * 4];
        float mn = fmaxf(m, a);
        float sc = __expf(m - mn), p = __expf(a - mn);
        l = l * sc + p;
        acc.x = acc.x * sc + p * bf2f(hun.x);
        acc.y = acc.y * sc + p * bf2f(hun.y);
        acc.z = acc.z * sc + p * bf2f(hun.z);
        acc.w = acc.w * sc + p * bf2f(hun.w);
    }
    if constexpr (IS_L1) {
        if (g == 0) {
            float4 o;
            o.x = acc.x / l + bias[s * 4 + 0];
            o.y = acc.y / l + bias[s * 4 + 1];
            o.z = acc.z / l + bias[s * 4 + 2];
            o.w = acc.w / l + bias[s * 4 + 3];
            o.x = o.x > 0.f ? o.x : expm1f(o.x);
            o.y = o.y > 0.f ? o.y : expm1f(o.y);
            o.z = o.z > 0.f ? o.z : expm1f(o.z);
            o.w = o.w > 0.f ? o.w : expm1f(o.w);
            sh_o[wv][s * 4 + 0] = o.x;
            sh_o[wv][s * 4 + 1] = o.y;
            sh_o[wv][s * 4 + 2] = o.z;
            sh_o[wv][s * 4 + 3] = o.w;
        }
        // wave-local LDS: same-wave ds ops are ordered; no barrier needed
        float h2 = 0.f;
        #pragma unroll 8
        for (int c = 0; c < 64; ++c)
            h2 += sh_o[wv][c] * W2[c * 64 + lane];
        float v1 = h2 * uv2[lane], v2 = h2 * uv2[64 + lane];
        #pragma unroll
        for (int off = 32; off; off >>= 1) {
            v1 += __shfl_xor(v1, off);
            v2 += __shfl_xor(v2, off);
        }
        if (lane == 0) { asrc2[n] = v1; adst2[n] = v2; }
        h2out[(long long)n * 64 + lane] = f2bf(h2);
    } else {
        if (g == 0) {
            float4 o;
            o.x = acc.x / l + bias[s * 4 + 0];
            o.y = acc.y / l + bias[s * 4 + 1];
            o.z = acc.z / l + bias[s * 4 + 2];
            o.w = acc.w / l + bias[s * 4 + 3];
            *(float4*)&outf[(long long)n * 64 + s * 4] = o;
        }
    }
}

// ============================================================
extern "C" void kernel_launch(void* const* d_in, const int* in_sizes, int n_in,
                              void* d_out, int out_size, void* d_ws, size_t ws_size,
                              hipStream_t stream) {
    const float* x     = (const float*)d_in[0];
    const int*   eidx  = (const int*)d_in[1];
    const float* eattr = (const float*)d_in[2];
    const int*   batch = (const int*)d_in[3];
    const float* W1 = (const float*)d_in[4];
    const float* as1 = (const float*)d_in[5];
    const float* ad1 = (const float*)d_in[6];
    const float* We1 = (const float*)d_in[7];
    const float* vae1 = (const float*)d_in[8];
    const float* b1  = (const float*)d_in[9];
    const float* W2 = (const float*)d_in[10];
    const float* as2 = (const float*)d_in[11];
    const float* ad2 = (const float*)d_in[12];
    const float* We2 = (const float*)d_in[13];
    const float* vae2 = (const float*)d_in[14];
    const float* b2  = (const float*)d_in[15];
    const float* Wm1 = (const float*)d_in[16];
    const float* bm1 = (const float*)d_in[17];
    const float* Wm2 = (const float*)d_in[18];
    const float* bm2 = (const float*)d_in[19];

    const int* src = eidx;
    const int* dst = eidx + NE;

    float* out_h = (float*)d_out;
    float* out_e = out_h + (long long)NN * C;
    float* out_b = out_e + (long long)NE * C;

    // workspace
    uint2* csr    = (uint2*)d_ws;                       // NE (8 B records)
    float* ae1    = (float*)(csr + NE);                 // NE
    float* ae2    = ae1 + NE;                           // NE
    unsigned short* h2 = (unsigned short*)(ae2 + NE);   // NN*64 bf16 (layer-2 feats)
    unsigned short* h = h2 + (long long)NN * C;         // NN*64 bf16 (layer-1 feats)
    float* asrc   = (float*)(h + (long long)NN * C);    // NN
    float* adst   = asrc + NN;                          // NN
    float* asrc2  = adst + NN;                          // NN
    float* adst2  = asrc2 + NN;                         // NN
    float* vecs   = adst2 + NN;                         // 512
    int*   hist   = (int*)(vecs + 512);                 // NN
    int*   row_ptr= hist + NN;                          // NN+1
    int*   cursor = row_ptr + NN + 1;                   // NN
    int*   bagg   = cursor + NN;                        // NB

    // setup: zero hist/bagg, vecs, batch passthrough
    k_setup<<<NB, 256, 0, stream>>>(We1, vae1, We2, vae2, W1, as1, ad1,
                                    W2, as2, ad2, batch, vecs, hist, bagg, out_b);

    // fused: edge MLP (+ae dots +hist) overlapped with feat1 (h, asrc, adst)
    k_mlp_feat<<<FEATB + NE / 128, 256, 0, stream>>>(
        eattr, dst, Wm1, bm1, Wm2, bm2, vecs, out_e, ae1, ae2, hist,
        x, W1, vecs + 128, h, asrc, adst);

    // CSR build: single-kernel scan + scatter
    k_scan_f<<<NB, 256, 0, stream>>>(hist, row_ptr, cursor, bagg);
    k_scatter<<<(NE + 255) / 256, 256, 0, stream>>>(src, dst, ae1, ae2, cursor, csr);

    // GAT layer 1 + fused layer-2 projection (h2, asrc2, adst2)
    k_gat<true><<<(NN + 3) / 4, 256, 0, stream>>>(row_ptr, csr, asrc, adst, h, b1,
                                                  W2, vecs + 384, h2, asrc2, adst2,
                                                  nullptr);

    // GAT layer 2
    k_gat<false><<<(NN + 3) / 4, 256, 0, stream>>>(row_ptr, csr, asrc2, adst2, h2, b2,
                                                   nullptr, nullptr, nullptr, nullptr,
                                                   nullptr, out_h);
}

// Round 18
// 265.133 us; speedup vs baseline: 1.0159x; 1.0159x over previous
//
#include <hip/hip_runtime.h>

constexpr int NN = 50000;
constexpr int NE = 800000;
constexpr int C = 64;        // EIN == HID == OUT == 64
constexpr int IN_DIM = 128;
constexpr float NEG = 0.2f;
constexpr int NB = (NN + 255) / 256;     // 196 blocks
constexpr int FEATB = (NN + 127) / 128;  // 391 feat blocks

typedef __attribute__((ext_vector_type(8))) short short8;
typedef __attribute__((ext_vector_type(4))) float f32x4;

// ---- pure-integer bf16 conversions (no HIP bf16 structs) ----
__device__ __forceinline__ unsigned short f2bf(float f) {
    unsigned u = __float_as_uint(f);
    unsigned r = 0x7FFFu + ((u >> 16) & 1u);
    return (unsigned short)((u + r) >> 16);
}
__device__ __forceinline__ unsigned pack_bf2(float a, float b) {
    return (unsigned)f2bf(a) | ((unsigned)f2bf(b) << 16);
}
__device__ __forceinline__ float bf2f(unsigned u) {
    return __uint_as_float(u << 16);
}

// ============================================================
// Fused setup: zero hist/bagg, batch passthrough, small vecs.
// ============================================================
__global__ __launch_bounds__(256) void k_setup(
        const float* __restrict__ We1, const float* __restrict__ ae1v,
        const float* __restrict__ We2, const float* __restrict__ ae2v,
        const float* __restrict__ W1, const float* __restrict__ as1,
        const float* __restrict__ ad1,
        const float* __restrict__ W2, const float* __restrict__ as2,
        const float* __restrict__ ad2,
        const int* __restrict__ batch,
        float* __restrict__ vecs, int* __restrict__ hist, int* __restrict__ bagg,
        float* __restrict__ out_b) {
    int t = blockIdx.x * 256 + threadIdx.x;
    if (t < 512) {
        const float* M; const float* v; int row;
        if      (t < 64)  { M = We1; v = ae1v; row = t; }
        else if (t < 128) { M = We2; v = ae2v; row = t - 64; }
        else if (t < 256) { M = W1;  v = as1;  row = t - 128; }
        else if (t < 384) { M = W1;  v = ad1;  row = t - 256; }
        else if (t < 448) { M = W2;  v = as2;  row = t - 384; }
        else              { M = W2;  v = ad2;  row = t - 448; }
        float s = 0.f;
        #pragma unroll
        for (int c = 0; c < 64; ++c) s += M[row * 64 + c] * v[c];
        vecs[t] = s;
    }
    if (t < NN) { hist[t] = 0; out_b[t] = (float)batch[t]; }
    if (t < NB) bagg[t] = 0;
}

// ============================================================
// MLP body: fused 2-layer edge MLP via MFMA bf16 (swapped
// operands) + fp32 ae dots + dst hist. 128 edges, 256 threads.
// ============================================================
__device__ __forceinline__ void mlp_body(char* __restrict__ LDSB, int bid,
        const float* __restrict__ ea, const int* __restrict__ dst,
        const float* __restrict__ Wm1, const float* __restrict__ bm1,
        const float* __restrict__ Wm2, const float* __restrict__ bm2,
        const float* __restrict__ wv,
        float* __restrict__ eout, float* __restrict__ ae1, float* __restrict__ ae2,
        int* __restrict__ hist) {
    constexpr int AP = 144;              // bytes per LDS row: (64+8) bf16
    char* Atile = LDSB;                  // 18 KB
    char* Bt1 = LDSB + 128 * AP;         // 9 KB
    char* Bt2 = Bt1 + 64 * AP;           // 9 KB
    const int t = threadIdx.x;
    const long long E0 = (long long)bid * 128;
    const int l = t & 63;

    if (t < 128) atomicAdd(&hist[dst[E0 + t]], 1);

    // stage A tile (coalesced nt float4) + fp32 ae dots
    {
        const int j = t & 15;
        const int eb = t >> 4;
        float4 wk1 = *(const float4*)&wv[j * 4];
        float4 wk2 = *(const float4*)&wv[64 + j * 4];
        const f32x4* g = (const f32x4*)(ea + E0 * 64);
        float s1[8], s2[8];
        #pragma unroll
        for (int q = 0; q < 8; ++q) {
            f32x4 v = __builtin_nontemporal_load(&g[t + 256 * q]);
            int e = eb + 16 * q;
            s1[q] = v[0] * wk1.x + v[1] * wk1.y + v[2] * wk1.z + v[3] * wk1.w;
            s2[q] = v[0] * wk2.x + v[1] * wk2.y + v[2] * wk2.z + v[3] * wk2.w;
            uint2 wr;
            wr.x = pack_bf2(v[0], v[1]);
            wr.y = pack_bf2(v[2], v[3]);
            *(uint2*)(Atile + e * AP + j * 8) = wr;
        }
        #pragma unroll
        for (int off = 1; off < 16; off <<= 1) {
            #pragma unroll
            for (int q = 0; q < 8; ++q) {
                s1[q] += __shfl_xor(s1[q], off);
                s2[q] += __shfl_xor(s2[q], off);
            }
        }
        float o1 = 0.f, o2 = 0.f;
        #pragma unroll
        for (int q = 0; q < 8; ++q) {
            if (j == q)     o1 = s1[q];
            if (j == q + 8) o2 = s2[q];
        }
        if (j < 8) ae1[E0 + eb + 16 * j] = o1;
        else       ae2[E0 + eb + 16 * (j - 8)] = o2;
    }
    // stage Bt1/Bt2 = W^T bf16
    {
        const int c = t & 63, kq = t >> 6;
        #pragma unroll
        for (int i = 0; i < 16; i += 2) {
            int k = kq * 16 + i;
            *(unsigned*)(Bt1 + c * AP + k * 2) = pack_bf2(Wm1[k * 64 + c], Wm1[(k + 1) * 64 + c]);
            *(unsigned*)(Bt2 + c * AP + k * 2) = pack_bf2(Wm2[k * 64 + c], Wm2[(k + 1) * 64 + c]);
        }
    }
    __syncthreads();

    const int m0 = (t >> 6) * 32;
    const int lr = l & 15;
    const int lq = l >> 4;
    const int lk = lq * 8;

    f32x4 acc[4][2] = {};
    #pragma unroll
    for (int ks = 0; ks < 2; ++ks) {
        int ko = ks * 32 + lk;
        short8 a0 = *(const short8*)(Atile + (m0 + lr) * AP + ko * 2);
        short8 a1 = *(const short8*)(Atile + (m0 + 16 + lr) * AP + ko * 2);
        #pragma unroll
        for (int ct = 0; ct < 4; ++ct) {
            short8 b = *(const short8*)(Bt1 + (ct * 16 + lr) * AP + ko * 2);
            acc[ct][0] = __builtin_amdgcn_mfma_f32_16x16x32_bf16(b, a0, acc[ct][0], 0, 0, 0);
            acc[ct][1] = __builtin_amdgcn_mfma_f32_16x16x32_bf16(b, a1, acc[ct][1], 0, 0, 0);
        }
    }
    #pragma unroll
    for (int ct = 0; ct < 4; ++ct) {
        float4 bv = *(const float4*)&bm1[ct * 16 + lq * 4];
        #pragma unroll
        for (int et = 0; et < 2; ++et) {
            float v0 = fmaxf(acc[ct][et][0] + bv.x, 0.f);
            float v1 = fmaxf(acc[ct][et][1] + bv.y, 0.f);
            float v2 = fmaxf(acc[ct][et][2] + bv.z, 0.f);
            float v3 = fmaxf(acc[ct][et][3] + bv.w, 0.f);
            uint2 w;
            w.x = pack_bf2(v0, v1);
            w.y = pack_bf2(v2, v3);
            int e = m0 + et * 16 + lr;
            *(uint2*)(Atile + e * AP + (ct * 16 + lq * 4) * 2) = w;
        }
    }
    f32x4 acc2[4][2] = {};
    #pragma unroll
    for (int ks = 0; ks < 2; ++ks) {
        int ko = ks * 32 + lk;
        short8 a0 = *(const short8*)(Atile + (m0 + lr) * AP + ko * 2);
        short8 a1 = *(const short8*)(Atile + (m0 + 16 + lr) * AP + ko * 2);
        #pragma unroll
        for (int ct = 0; ct < 4; ++ct) {
            short8 b = *(const short8*)(Bt2 + (ct * 16 + lr) * AP + ko * 2);
            acc2[ct][0] = __builtin_amdgcn_mfma_f32_16x16x32_bf16(b, a0, acc2[ct][0], 0, 0, 0);
            acc2[ct][1] = __builtin_amdgcn_mfma_f32_16x16x32_bf16(b, a1, acc2[ct][1], 0, 0, 0);
        }
    }
    #pragma unroll
    for (int ct = 0; ct < 4; ++ct) {
        float4 bv = *(const float4*)&bm2[ct * 16 + lq * 4];
        #pragma unroll
        for (int et = 0; et < 2; ++et) {
            int e = m0 + et * 16 + lr;
            float4 o;
            o.x = acc2[ct][et][0] + bv.x;
            o.y = acc2[ct][et][1] + bv.y;
            o.z = acc2[ct][et][2] + bv.z;
            o.w = acc2[ct][et][3] + bv.w;
            *(float4*)&eout[(E0 + e) * 64 + ct * 16 + lq * 4] = o;
        }
    }
}

// ============================================================
// feat body: h = X @ W (MFMA bf16 swapped, bf16-packed out) +
// fp32 dots. 128 rows, 256 threads. BF16IN: packed bf16 input.
// ============================================================
template <int K, bool BF16IN>
__device__ __forceinline__ void feat_body(char* __restrict__ LDSB, int bid,
        const void* __restrict__ xv, const float* __restrict__ W,
        const float* __restrict__ uv,
        unsigned short* __restrict__ h, float* __restrict__ asrc,
        float* __restrict__ adst, int M) {
    constexpr int AP = K * 2 + 16;
    constexpr int QW = K / 4;
    constexpr int NQ = K / 8;
    constexpr int EPQ = 256 / QW;
    char* Atile = LDSB;
    char* Bt = LDSB + 128 * AP;
    const int t = threadIdx.x;
    const int M0 = bid * 128;
    const int l = t & 63;

    {
        const int j = t % QW;
        const int eb = t / QW;
        float4 wk1 = *(const float4*)&uv[j * 4];
        float4 wk2 = *(const float4*)&uv[K + j * 4];
        float s1[NQ], s2[NQ];
        #pragma unroll
        for (int q = 0; q < NQ; ++q) {
            int e = eb + EPQ * q;
            float v0, v1, v2, v3;
            uint2 wr;
            if constexpr (BF16IN) {
                const uint2* g = (const uint2*)xv + (long long)M0 * (K / 4);
                uint2 w = make_uint2(0u, 0u);
                if (M0 + e < M) w = g[t + 256 * q];
                v0 = bf2f(w.x & 0xFFFFu); v1 = bf2f(w.x >> 16);
                v2 = bf2f(w.y & 0xFFFFu); v3 = bf2f(w.y >> 16);
                wr = w;
            } else {
                const float4* g = (const float4*)xv + (long long)M0 * (K / 4);
                float4 v = make_float4(0.f, 0.f, 0.f, 0.f);
                if (M0 + e < M) v = g[t + 256 * q];
                v0 = v.x; v1 = v.y; v2 = v.z; v3 = v.w;
                wr.x = pack_bf2(v.x, v.y);
                wr.y = pack_bf2(v.z, v.w);
            }
            s1[q] = v0 * wk1.x + v1 * wk1.y + v2 * wk1.z + v3 * wk1.w;
            s2[q] = v0 * wk2.x + v1 * wk2.y + v2 * wk2.z + v3 * wk2.w;
            *(uint2*)(Atile + e * AP + j * 8) = wr;
        }
        #pragma unroll
        for (int off = 1; off < QW; off <<= 1) {
            #pragma unroll
            for (int q = 0; q < NQ; ++q) {
                s1[q] += __shfl_xor(s1[q], off);
                s2[q] += __shfl_xor(s2[q], off);
            }
        }
        float o1 = 0.f, o2 = 0.f;
        #pragma unroll
        for (int q = 0; q < NQ; ++q) {
            if (j == q)      o1 = s1[q];
            if (j == q + NQ) o2 = s2[q];
        }
        if (j < NQ) { int e = eb + EPQ * j;        if (M0 + e < M) asrc[M0 + e] = o1; }
        else        { int e = eb + EPQ * (j - NQ); if (M0 + e < M) adst[M0 + e] = o2; }
    }
    {
        const int c = t & 63, kq = t >> 6;
        #pragma unroll
        for (int i = 0; i < K / 4; i += 2) {
            int k = kq * (K / 4) + i;
            *(unsigned*)(Bt + c * AP + k * 2) = pack_bf2(W[k * 64 + c], W[(k + 1) * 64 + c]);
        }
    }
    __syncthreads();

    const int m0 = (t >> 6) * 32;
    const int lr = l & 15;
    const int lq = l >> 4;
    const int lk = lq * 8;

    f32x4 acc[4][2] = {};
    #pragma unroll
    for (int ks = 0; ks < K / 32; ++ks) {
        int ko = ks * 32 + lk;
        short8 a0 = *(const short8*)(Atile + (m0 + lr) * AP + ko * 2);
        short8 a1 = *(const short8*)(Atile + (m0 + 16 + lr) * AP + ko * 2);
        #pragma unroll
        for (int ct = 0; ct < 4; ++ct) {
            short8 b = *(const short8*)(Bt + (ct * 16 + lr) * AP + ko * 2);
            acc[ct][0] = __builtin_amdgcn_mfma_f32_16x16x32_bf16(b, a0, acc[ct][0], 0, 0, 0);
            acc[ct][1] = __builtin_amdgcn_mfma_f32_16x16x32_bf16(b, a1, acc[ct][1], 0, 0, 0);
        }
    }
    #pragma unroll
    for (int ct = 0; ct < 4; ++ct)
    #pragma unroll
    for (int et = 0; et < 2; ++et) {
        int row = m0 + et * 16 + lr;
        if (M0 + row < M) {
            uint2 w;
            w.x = pack_bf2(acc[ct][et][0], acc[ct][et][1]);
            w.y = pack_bf2(acc[ct][et][2], acc[ct][et][3]);
            *(uint2*)&h[(long long)(M0 + row) * 64 + ct * 16 + lq * 4] = w;
        }
    }
}

// ============================================================
// Fused launch: blocks [0,FEATB) run feat1 (independent of the
// MLP pipeline), rest run MLP — overlap under memory streaming.
// ============================================================
__global__ __launch_bounds__(256) void k_mlp_feat(
        const float* __restrict__ ea, const int* __restrict__ dst,
        const float* __restrict__ Wm1, const float* __restrict__ bm1,
        const float* __restrict__ Wm2, const float* __restrict__ bm2,
        const float* __restrict__ wv,
        float* __restrict__ eout, float* __restrict__ ae1, float* __restrict__ ae2,
        int* __restrict__ hist,
        const float* __restrict__ x, const float* __restrict__ W1,
        const float* __restrict__ uv,
        unsigned short* __restrict__ h, float* __restrict__ asrc,
        float* __restrict__ adst) {
    __shared__ char LDSB[128 * (IN_DIM * 2 + 16) + 64 * (IN_DIM * 2 + 16)]; // 52224 B
    if (blockIdx.x < FEATB) {
        feat_body<IN_DIM, false>(LDSB, blockIdx.x, x, W1, uv, h, asrc, adst, NN);
    } else {
        mlp_body(LDSB, blockIdx.x - FEATB, ea, dst, Wm1, bm1, Wm2, bm2, wv,
                 eout, ae1, ae2, hist);
    }
}

// standalone feat kernel for layer 2 (K=64, bf16 input)
__global__ __launch_bounds__(256) void k_feat2(
        const void* __restrict__ xv, const float* __restrict__ W,
        const float* __restrict__ uv,
        unsigned short* __restrict__ h, float* __restrict__ asrc,
        float* __restrict__ adst) {
    __shared__ char LDSB[128 * 144 + 64 * 144];   // 27648 B
    feat_body<C, true>(LDSB, blockIdx.x, xv, W, uv, h, asrc, adst, NN);
}

// ============================================================
// Single-kernel decoupled-lookback exclusive scan (G16-safe:
// all 196 blocks co-resident).
// ============================================================
__global__ __launch_bounds__(256) void k_scan_f(const int* __restrict__ hist,
        int* __restrict__ row_ptr, int* __restrict__ cursor, int* __restrict__ bagg) {
    __shared__ int s[256];
    __shared__ int red[5];
    const int t = threadIdx.x, b = blockIdx.x;
    const int idx = b * 256 + t;
    int v = (idx < NN) ? hist[idx] : 0;
    s[t] = v;
    __syncthreads();
    #pragma unroll
    for (int off = 1; off < 256; off <<= 1) {
        int x = (t >= off) ? s[t - off] : 0;
        __syncthreads();
        s[t] += x;
        __syncthreads();
    }
    if (t == 255)
        __hip_atomic_store(&bagg[b], (s[255] << 1) | 1,
                           __ATOMIC_RELEASE, __HIP_MEMORY_SCOPE_AGENT);
    int contrib = 0;
    if (t < b) {
        int a;
        do {
            a = __hip_atomic_load(&bagg[t], __ATOMIC_ACQUIRE, __HIP_MEMORY_SCOPE_AGENT);
        } while (!(a & 1));
        contrib = a >> 1;
    }
    #pragma unroll
    for (int off = 32; off; off >>= 1) contrib += __shfl_down(contrib, off);
    if ((t & 63) == 0) red[t >> 6] = contrib;
    __syncthreads();
    if (t == 0) red[4] = red[0] + red[1] + red[2] + red[3];
    __syncthreads();
    int offset = red[4];
    if (idx < NN) {
        int rp = offset + s[t] - v;
        row_ptr[idx] = rp;
        cursor[idx] = rp;
    }
    if (idx == NN) row_ptr[NN] = NE;
}

// scatter 8-byte records: {src, ae1|ae2 packed bf16}
__global__ void k_scatter(const int* __restrict__ src, const int* __restrict__ dst,
                          const float* __restrict__ ae1, const float* __restrict__ ae2,
                          int* __restrict__ cursor, uint2* __restrict__ csr) {
    int t = blockIdx.x * blockDim.x + threadIdx.x;
    if (t >= NE) return;
    int d = dst[t];
    int pos = atomicAdd(&cursor[d], 1);
    csr[pos] = make_uint2((unsigned)src[t], pack_bf2(ae1[t], ae2[t]));
}

// ============================================================
// GAT aggregation: wave per node, 8 subgroups of 8 lanes each
// (8 edges in flight -> serial gather chain halved vs 4x16).
// IS_L1: output packed bf16 (layer-2 input); else fp32 (d_out).
// ============================================================
template <bool IS_L1>
__global__ void k_gat(const int* __restrict__ row_ptr, const uint2* __restrict__ csr,
                      const float* __restrict__ asrc, const float* __restrict__ adst,
                      const unsigned short* __restrict__ h, const float* __restrict__ bias,
                      void* __restrict__ outv) {
    int n = blockIdx.x * 4 + (threadIdx.x >> 6);
    if (n >= NN) return;
    int lane = threadIdx.x & 63;
    int g = lane >> 3, s = lane & 7;     // 8 subgroups x 8 lanes
    int beg = row_ptr[n], end = row_ptr[n + 1];
    float adn = adst[n];
    float m = -1e30f, l = 0.f, sum_ae = 0.f;
    float acc[8] = {};

    int i = beg + g;
    uint2 rc = make_uint2(0u, 0u);
    uint4 hu = make_uint4(0u, 0u, 0u, 0u);
    float asv = 0.f;
    if (i < end) {
        rc = csr[i];
        hu = *(const uint4*)&h[(long long)rc.x * 64 + s * 8];
        asv = asrc[rc.x];
    }
    for (; i < end; i += 8) {
        uint2 rn = rc; uint4 hn = hu; float asn = asv;
        if (i + 8 < end) {
            rn = csr[i + 8];
            hn = *(const uint4*)&h[(long long)rn.x * 64 + s * 8];
            asn = asrc[rn.x];
        }
        float ae = IS_L1 ? bf2f(rc.y & 0xFFFFu) : bf2f(rc.y >> 16);
        sum_ae += ae;
        float a = asv + adn + ae;
        a = a > 0.f ? a : NEG * a;
        float mn = fmaxf(m, a);
        float sc = __expf(m - mn), p = __expf(a - mn);
        l = l * sc + p;
        float hv[8] = {bf2f(hu.x & 0xFFFFu), bf2f(hu.x >> 16),
                       bf2f(hu.y & 0xFFFFu), bf2f(hu.y >> 16),
                       bf2f(hu.z & 0xFFFFu), bf2f(hu.z >> 16),
                       bf2f(hu.w & 0xFFFFu), bf2f(hu.w >> 16)};
        #pragma unroll
        for (int j = 0; j < 8; ++j) acc[j] = acc[j] * sc + p * hv[j];
        m = mn;
        rc = rn; hu = hn; asv = asn;
    }
    // merge the 8 subgroups
    #pragma unroll
    for (int off = 8; off < 64; off <<= 1) {
        float mo = __shfl_xor(m, off);
        float lo = __shfl_xor(l, off);
        float so = __shfl_xor(sum_ae, off);
        float ao[8];
        #pragma unroll
        for (int j = 0; j < 8; ++j) ao[j] = __shfl_xor(acc[j], off);
        float mn = fmaxf(m, mo);
        float s1 = __expf(m - mn), s2 = __expf(mo - mn);
        l = l * s1 + lo * s2;
        #pragma unroll
        for (int j = 0; j < 8; ++j) acc[j] = acc[j] * s1 + ao[j] * s2;
        sum_ae += so;
        m = mn;
    }
    // self loop (ae_self = mean of incoming ae, by linearity)
    {
        float deg = (float)(end - beg);
        float ae = sum_ae / fmaxf(deg, 1.f);
        float a = asrc[n] + adn + ae;
        a = a > 0.f ? a : NEG * a;
        uint4 hun = *(const uint4*)&h[(long long)n * 64 + s * 8];
        float mn = fmaxf(m, a);
        float sc = __expf(m - mn), p = __expf(a - mn);
        l = l * sc + p;
        float hv[8] = {bf2f(hun.x & 0xFFFFu), bf2f(hun.x >> 16),
                       bf2f(hun.y & 0xFFFFu), bf2f(hun.y >> 16),
                       bf2f(hun.z & 0xFFFFu), bf2f(hun.z >> 16),
                       bf2f(hun.w & 0xFFFFu), bf2f(hun.w >> 16)};
        #pragma unroll
        for (int j = 0; j < 8; ++j) acc[j] = acc[j] * sc + p * hv[j];
    }
    if (g == 0) {
        float o[8];
        #pragma unroll
        for (int j = 0; j < 8; ++j) o[j] = acc[j] / l + bias[s * 8 + j];
        if (IS_L1) {
            #pragma unroll
            for (int j = 0; j < 8; ++j) o[j] = o[j] > 0.f ? o[j] : expm1f(o[j]);
            uint4 w;
            w.x = pack_bf2(o[0], o[1]);
            w.y = pack_bf2(o[2], o[3]);
            w.z = pack_bf2(o[4], o[5]);
            w.w = pack_bf2(o[6], o[7]);
            *(uint4*)&((unsigned short*)outv)[(long long)n * 64 + s * 8] = w;
        } else {
            float* op = (float*)outv + (long long)n * 64 + s * 8;
            *(float4*)op       = make_float4(o[0], o[1], o[2], o[3]);
            *(float4*)(op + 4) = make_float4(o[4], o[5], o[6], o[7]);
        }
    }
}

// ============================================================
extern "C" void kernel_launch(void* const* d_in, const int* in_sizes, int n_in,
                              void* d_out, int out_size, void* d_ws, size_t ws_size,
                              hipStream_t stream) {
    const float* x     = (const float*)d_in[0];
    const int*   eidx  = (const int*)d_in[1];
    const float* eattr = (const float*)d_in[2];
    const int*   batch = (const int*)d_in[3];
    const float* W1 = (const float*)d_in[4];
    const float* as1 = (const float*)d_in[5];
    const float* ad1 = (const float*)d_in[6];
    const float* We1 = (const float*)d_in[7];
    const float* vae1 = (const float*)d_in[8];
    const float* b1  = (const float*)d_in[9];
    const float* W2 = (const float*)d_in[10];
    const float* as2 = (const float*)d_in[11];
    const float* ad2 = (const float*)d_in[12];
    const float* We2 = (const float*)d_in[13];
    const float* vae2 = (const float*)d_in[14];
    const float* b2  = (const float*)d_in[15];
    const float* Wm1 = (const float*)d_in[16];
    const float* bm1 = (const float*)d_in[17];
    const float* Wm2 = (const float*)d_in[18];
    const float* bm2 = (const float*)d_in[19];

    const int* src = eidx;
    const int* dst = eidx + NE;

    float* out_h = (float*)d_out;
    float* out_e = out_h + (long long)NN * C;
    float* out_b = out_e + (long long)NE * C;

    // workspace
    uint2* csr    = (uint2*)d_ws;                       // NE (8 B records)
    float* ae1    = (float*)(csr + NE);                 // NE
    float* ae2    = ae1 + NE;                           // NE
    unsigned short* out1b = (unsigned short*)(ae2 + NE);        // NN*64 bf16
    unsigned short* h = out1b + (long long)NN * C;              // NN*64 bf16
    float* asrc   = (float*)(h + (long long)NN * C);    // NN
    float* adst   = asrc + NN;                          // NN
    float* vecs   = adst + NN;                          // 512
    int*   hist   = (int*)(vecs + 512);                 // NN
    int*   row_ptr= hist + NN;                          // NN+1
    int*   cursor = row_ptr + NN + 1;                   // NN
    int*   bagg   = cursor + NN;                        // NB

    // setup: zero hist/bagg, vecs, batch passthrough
    k_setup<<<NB, 256, 0, stream>>>(We1, vae1, We2, vae2, W1, as1, ad1,
                                    W2, as2, ad2, batch, vecs, hist, bagg, out_b);

    // fused: edge MLP (+ae dots +hist) overlapped with feat1 (h, asrc, adst)
    k_mlp_feat<<<FEATB + NE / 128, 256, 0, stream>>>(
        eattr, dst, Wm1, bm1, Wm2, bm2, vecs, out_e, ae1, ae2, hist,
        x, W1, vecs + 128, h, asrc, adst);

    // CSR build: single-kernel scan + scatter
    k_scan_f<<<NB, 256, 0, stream>>>(hist, row_ptr, cursor, bagg);
    k_scatter<<<(NE + 255) / 256, 256, 0, stream>>>(src, dst, ae1, ae2, cursor, csr);

    // GAT layer 1
    k_gat<true><<<(NN + 3) / 4, 256, 0, stream>>>(row_ptr, csr, asrc, adst, h, b1, out1b);

    // GAT layer 2 (bf16 input)
    k_feat2<<<FEATB, 256, 0, stream>>>(out1b, W2, vecs + 384, h, asrc, adst);
    k_gat<false><<<(NN + 3) / 4, 256, 0, stream>>>(row_ptr, csr, asrc, adst, h, b2, out_h);
}